// Round 3
// baseline (113.782 us; speedup 1.0000x reference)
//
#include <hip/hip_runtime.h>
#include <cfloat>

// BottomRightPool: out[b,c,i,j] = max(x[b,c,:i+1,:j+1])
// = cummax over H (axis 2) then cummax over W (axis 3).
//
// One wave (64 lanes) per (b,c) image of 128x128 fp32.
// Lane j owns columns 2j and 2j+1 (float2 loads/stores -> 512B coalesced row).
// Per row: update running column max (H-cummax), then a wave-level
// inclusive max-scan over the 128 columns (W-cummax), then store.

__global__ __launch_bounds__(64)
void BottomRightPool_54357106098213_kernel(const float* __restrict__ x,
                                           float* __restrict__ out) {
    const size_t img = blockIdx.x;              // b*256 + c, 0..4095
    const int lane = threadIdx.x;               // 0..63

    const float2* __restrict__ xi =
        reinterpret_cast<const float2*>(x + img * (size_t)(128 * 128));
    float2* __restrict__ oi =
        reinterpret_cast<float2*>(out + img * (size_t)(128 * 128));

    // Running column maxima for columns 2*lane and 2*lane+1.
    float cm0 = -FLT_MAX;
    float cm1 = -FLT_MAX;

    #pragma unroll 4
    for (int i = 0; i < 128; ++i) {
        // --- load row i (coalesced: 64 lanes x 8B = full 512B row) ---
        float2 v = xi[i * 64 + lane];

        // --- H-cummax: per-column running max ---
        cm0 = fmaxf(cm0, v.x);
        cm1 = fmaxf(cm1, v.y);

        // --- W-cummax over the 128-wide row (a0,b0,a1,b1,...):
        // p_j = max(a_j, b_j); E_j = exclusive max-scan of p;
        // out_a_j = max(E_j, a_j); out_b_j = max(E_j, p_j).
        float p = fmaxf(cm0, cm1);

        // Inclusive max-scan of p across the 64-lane wave (Hillis-Steele).
        float s = p;
        #pragma unroll
        for (int off = 1; off < 64; off <<= 1) {
            float t = __shfl_up(s, off, 64);
            s = fmaxf(s, (lane >= off) ? t : -FLT_MAX);
        }
        // Exclusive value: inclusive of lane-1 (lane 0 -> -inf).
        float e = __shfl_up(s, 1, 64);
        if (lane == 0) e = -FLT_MAX;

        float2 o;
        o.x = fmaxf(e, cm0);
        o.y = fmaxf(e, p);

        // --- store row i (coalesced) ---
        oi[i * 64 + lane] = o;
    }
}

extern "C" void kernel_launch(void* const* d_in, const int* in_sizes, int n_in,
                              void* d_out, int out_size, void* d_ws, size_t ws_size,
                              hipStream_t stream) {
    const float* x = (const float*)d_in[0];
    float* out = (float*)d_out;

    // 16 batches * 256 channels = 4096 independent 128x128 images.
    dim3 grid(16 * 256);
    dim3 block(64);
    BottomRightPool_54357106098213_kernel<<<grid, block, 0, stream>>>(x, out);
}